// Round 1
// baseline (402.185 us; speedup 1.0000x reference)
//
#include <hip/hip_runtime.h>
#include <math.h>

#define NF 32
#define NN 4096
#define ND 64
#define NK 512

// loss = q_latent + 0.25 * e_latent = 1.25 * mean((q - x)^2)
#define LOSS_SCALE (1.25f / (float)(NF * NN * ND))
// rescue margin: rows with approx top-2 gap < TAU get exact fp32 re-argmin.
// 3-term split-bf16 score error: fp32-accum noise ~3e-5 + dropped lo*lo term
// <~1e-5; col-pack trunc e_t ~ 6e-5. Bound 4*e_a + 2*e_t ~ 2.6e-4 -> TAU 3e-4.
#define TAU 3e-4f

#define NPARTIAL (NF * NN * 4 / 256)   // 2048 gather blocks

typedef short bf16x8 __attribute__((ext_vector_type(8)));
typedef float f32x4 __attribute__((ext_vector_type(4)));

static __device__ __forceinline__ unsigned short f2bf_rne(float f) {
    unsigned int u = __float_as_uint(f);
    u += 0x7FFFu + ((u >> 16) & 1u);
    return (unsigned short)(u >> 16);
}
static __device__ __forceinline__ float bf2f(unsigned short h) {
    return __uint_as_float(((unsigned int)h) << 16);
}

// async global->LDS: 16B per lane, dest = wave-uniform base + lane*16
static __device__ __forceinline__ void gload_lds16(const void* g, void* l) {
    __builtin_amdgcn_global_load_lds(
        (const __attribute__((address_space(1))) unsigned int*)g,
        (__attribute__((address_space(3))) unsigned int*)l, 16, 0, 0);
}

// ---------------------------------------------------------------------------
// prep_w (fused): wt[f][k][d] = w[f][d][k]; wh/wl bf16 split; w2h = 0.5||w||^2
// via 8-lane shuffle reduce. thread per (f,k,dc): 512 blocks.
// ---------------------------------------------------------------------------
__global__ __launch_bounds__(256)
void vq_prep_w(const float* __restrict__ w, float* __restrict__ wt,
               unsigned short* __restrict__ wh, unsigned short* __restrict__ wl,
               float* __restrict__ w2h) {
    const int gid = blockIdx.x * 256 + threadIdx.x;   // [0, NF*NK*8)
    const int dc = gid & 7;
    const int k  = (gid >> 3) & (NK - 1);
    const int f  = gid >> 12;
    const float* __restrict__ wf = w + (size_t)f * ND * NK;
    const size_t rowo = ((size_t)f * NK + k) * ND + dc * 8;

    float v[8];
    unsigned short hh[8], ll[8];
    float s = 0.0f;
#pragma unroll
    for (int j = 0; j < 8; ++j) {
        v[j] = wf[(dc * 8 + j) * NK + k];
        s = fmaf(v[j], v[j], s);
        hh[j] = f2bf_rne(v[j]);
        ll[j] = f2bf_rne(v[j] - bf2f(hh[j]));
    }
    *(float4*)(wt + rowo)     = make_float4(v[0], v[1], v[2], v[3]);
    *(float4*)(wt + rowo + 4) = make_float4(v[4], v[5], v[6], v[7]);
    *(ushort4*)(wh + rowo)     = make_ushort4(hh[0], hh[1], hh[2], hh[3]);
    *(ushort4*)(wh + rowo + 4) = make_ushort4(hh[4], hh[5], hh[6], hh[7]);
    *(ushort4*)(wl + rowo)     = make_ushort4(ll[0], ll[1], ll[2], ll[3]);
    *(ushort4*)(wl + rowo + 4) = make_ushort4(ll[4], ll[5], ll[6], ll[7]);

    s += __shfl_xor(s, 1, 64);
    s += __shfl_xor(s, 2, 64);
    s += __shfl_xor(s, 4, 64);
    if (dc == 0) w2h[f * NK + k] = 0.5f * s;
}

// ---------------------------------------------------------------------------
// argmin v2: COLUMN-SPLIT for occupancy. Block = 512 threads = 8 waves:
// wave w -> row-group rg = w>>1 (32 rows), col-half h = w&1 (256 cols).
// Total waves 8192 -> 32 waves/CU (8/SIMD), 2x the old structure; the old
// kernel sat at 29% occupancy with every pipe <45% busy (latency-bound).
// Per iteration i in [0,8): stage supertile pair {i, 8+i} (one per half),
// dbuf; each wave computes its half's supertile. 8 barriers vs 16.
// 3-term split MFMA (xh*wh + xh*wl + xl*wh): lo*lo term <= ~1e-5, inside the
// TAU cushion; -25% MFMA work. acc init +0.5||w_k||^2 -> c IS the score.
// Exact top-2 (m1/m2) for the rescue flag + packed-key kmin for the index;
// col-halves merged through a 3KB LDS buffer at the end.
// grid: 1024 blocks, XCD-swizzled.
// ---------------------------------------------------------------------------
__global__ __launch_bounds__(512, 8)
void vq_argmin(const float* __restrict__ x_in,
               const unsigned short* __restrict__ wh,
               const unsigned short* __restrict__ wl,
               const float* __restrict__ w2h,
               unsigned int* __restrict__ keys,
               unsigned char* __restrict__ flags) {
    const int b    = blockIdx.x;          // [0, 1024)
    const int j    = b >> 3;              // [0, 128)
    const int f    = (b & 7) * 4 + (j & 3);
    const int xt   = j >> 2;              // [0, 32)
    const int tid  = threadIdx.x;
    const int wave = tid >> 6;            // [0, 8)
    const int lane = tid & 63;
    const int lc   = lane & 15;
    const int q    = lane >> 4;
    const int h    = wave & 1;            // column half
    const int rg   = wave >> 1;           // row group [0, 4)
    const int n0   = xt * 128 + rg * 32;  // wave's private 32 rows

    __shared__ float w2s[NK];                                  // 2 KB
    __shared__ __align__(16) unsigned short bstage[2][2][4096]; // 2 x 2 x 8 KB
    __shared__ float smrg[3][2][128];                          // 3 KB

    w2s[tid & (NK - 1)] = w2h[f * NK + (tid & (NK - 1))];

    // ---- A-frags: 32 rows' (-x), split to bf16 hi/lo in-register.
    bf16x8 ah[2][2], al[2][2];
    const float* __restrict__ xbase = x_in + ((size_t)f * NN + n0 + lc) * ND;
#pragma unroll
    for (int mt = 0; mt < 2; ++mt) {
#pragma unroll
        for (int s = 0; s < 2; ++s) {
            const float* p = xbase + mt * 16 * ND + s * 32 + q * 8;
            float4 u0 = *(const float4*)(p);
            float4 u1 = *(const float4*)(p + 4);
            float xv[8] = {-u0.x, -u0.y, -u0.z, -u0.w, -u1.x, -u1.y, -u1.z, -u1.w};
            bf16x8 hh, ll;
#pragma unroll
            for (int jj = 0; jj < 8; ++jj) {
                unsigned short hb = f2bf_rne(xv[jj]);
                unsigned short lb = f2bf_rne(xv[jj] - bf2f(hb));
                hh[jj] = (short)hb;
                ll[jj] = (short)lb;
            }
            ah[mt][s] = hh;
            al[mt][s] = ll;
        }
    }

    const unsigned short* __restrict__ whf = wh + (size_t)f * NK * ND;
    const unsigned short* __restrict__ wlf = wl + (size_t)f * NK * ND;

    float m1[8], m2[8], kmin[8];
#pragma unroll
    for (int ri = 0; ri < 8; ++ri) { m1[ri] = INFINITY; m2[ri] = INFINITY; kmin[ri] = INFINITY; }

    // ---- stage iteration i_: supertiles {i_} (half 0) and {8+i_} (half 1).
    // 16 chunks of 1KB, 2 per wave. chunk c: hh=c>>3, r=c&7 = tl*4+sg*2+a.
    // lane-linear dest (global_load_lds requirement).
#define STAGE(i_, pb) do {                                                  \
    _Pragma("unroll")                                                       \
    for (int rep = 0; rep < 2; ++rep) {                                     \
        const int c  = wave * 2 + rep;                                      \
        const int ch = c >> 3;                                              \
        const int r  = c & 7;                                               \
        const int tl = r >> 2;                                              \
        const int sg = (r >> 1) & 1;                                        \
        const int sti = ch * 8 + (i_);                                      \
        const unsigned short* src = ((r & 1) ? wlf : whf) +                 \
            (size_t)(sti * 32 + tl * 16 + lc) * ND + q * 8 + sg * 32;       \
        gload_lds16(src, &bstage[pb][ch][r * 512]);                         \
    }                                                                       \
} while (0)

    STAGE(0, 0);

    for (int i = 0; i < 8; ++i) {
        __syncthreads();                 // drains this iteration's loads
        if (i < 7) STAGE(i + 1, (i + 1) & 1);
        const unsigned short* __restrict__ bb = &bstage[i & 1][h][0];

#pragma unroll
        for (int tl = 0; tl < 2; ++tl) {
            const int col = (h * 8 + i) * 32 + tl * 16 + lc;
            bf16x8 bh0 = *(const bf16x8*)(bb + (tl * 4 + 0) * 512 + lane * 8);
            bf16x8 bl0 = *(const bf16x8*)(bb + (tl * 4 + 1) * 512 + lane * 8);
            bf16x8 bh1 = *(const bf16x8*)(bb + (tl * 4 + 2) * 512 + lane * 8);
            bf16x8 bl1 = *(const bf16x8*)(bb + (tl * 4 + 3) * 512 + lane * 8);
            const float w2 = w2s[col];
#pragma unroll
            for (int mt = 0; mt < 2; ++mt) {
                f32x4 c = {w2, w2, w2, w2};
                c = __builtin_amdgcn_mfma_f32_16x16x32_bf16(ah[mt][0], bh0, c, 0, 0, 0);
                c = __builtin_amdgcn_mfma_f32_16x16x32_bf16(ah[mt][1], bh1, c, 0, 0, 0);
                c = __builtin_amdgcn_mfma_f32_16x16x32_bf16(ah[mt][0], bl0, c, 0, 0, 0);
                c = __builtin_amdgcn_mfma_f32_16x16x32_bf16(ah[mt][1], bl1, c, 0, 0, 0);
                c = __builtin_amdgcn_mfma_f32_16x16x32_bf16(al[mt][0], bh0, c, 0, 0, 0);
                c = __builtin_amdgcn_mfma_f32_16x16x32_bf16(al[mt][1], bh1, c, 0, 0, 0);
#pragma unroll
                for (int r = 0; r < 4; ++r) {
                    const int ri = mt * 4 + r;
                    const float sc = c[r];
                    // idx channel: col packed into low 9 mantissa bits
                    const float key = __uint_as_float(
                        (__float_as_uint(sc) & 0xFFFFFE00u) | (unsigned int)col);
                    kmin[ri] = fminf(kmin[ri], key);
                    // flag channel: exact top-2
                    m2[ri] = __builtin_amdgcn_fmed3f(sc, m1[ri], m2[ri]);
                    m1[ri] = fminf(sc, m1[ri]);
                }
            }
        }
    }

    // ---- merge top-2 + kmin across the 16 lanes holding each row ----
#pragma unroll
    for (int ri = 0; ri < 8; ++ri) {
        float a1 = m1[ri], a2 = m2[ri], ak = kmin[ri];
#pragma unroll
        for (int off = 1; off < 16; off <<= 1) {
            const float b1 = __shfl_xor(a1, off, 64);
            const float b2 = __shfl_xor(a2, off, 64);
            const float bk = __shfl_xor(ak, off, 64);
            a2 = fminf(fminf(a2, b2), fmaxf(a1, b1));
            a1 = fminf(a1, b1);
            ak = fminf(ak, bk);
        }
        m1[ri] = a1; m2[ri] = a2; kmin[ri] = ak;
    }

    // ---- cross-wave (col-half) merge via LDS ----
    if (lc == 0) {
#pragma unroll
        for (int mt = 0; mt < 2; ++mt) {
#pragma unroll
            for (int r = 0; r < 4; ++r) {
                const int ri  = mt * 4 + r;
                const int row = rg * 32 + mt * 16 + q * 4 + r;
                smrg[0][h][row] = m1[ri];
                smrg[1][h][row] = m2[ri];
                smrg[2][h][row] = kmin[ri];
            }
        }
    }
    __syncthreads();

    if (tid < 128) {
        const float a1 = smrg[0][0][tid], b1 = smrg[0][1][tid];
        const float a2 = smrg[1][0][tid], b2 = smrg[1][1][tid];
        const float ka = smrg[2][0][tid], kb = smrg[2][1][tid];
        const float m1f = fminf(a1, b1);
        const float m2f = fminf(fminf(a2, b2), fmaxf(a1, b1));
        const float kf  = fminf(ka, kb);
        const int g = f * NN + xt * 128 + tid;
        keys[g]  = __float_as_uint(kf) & 0x1FFu;
        flags[g] = (m2f - m1f < TAU) ? 1 : 0;
    }
}

// ---------------------------------------------------------------------------
// rescue: exact fp32 full-K argmin for flagged rows. One wave per 16-row
// group (8192 waves: fine-grained -> small Poisson straggler tail). Ballot
// the flags, full-wave rescan per set row. No atomics.
// grid: 2048 blocks.
// ---------------------------------------------------------------------------
__global__ __launch_bounds__(256)
void vq_rescue(const float* __restrict__ x_in, const float* __restrict__ wt,
               const float* __restrict__ w2h,
               const unsigned char* __restrict__ flags,
               unsigned int* __restrict__ keys) {
    const int lane = threadIdx.x & 63;
    const int wid  = (blockIdx.x * 256 + threadIdx.x) >> 6;  // [0, 8192)
    const int base = wid * 16;

    const unsigned char flv = flags[base + (lane & 15)];
    unsigned long long m = __ballot(flv != 0 && lane < 16);
    while (m) {
        const int r = __ffsll(m) - 1;
        m &= m - 1;
        const int g = base + r;
        const int f = g >> 12;                               // / NN
        const float* __restrict__ xr  = x_in + (size_t)g * ND;
        const float* __restrict__ wtf = wt + (size_t)f * NK * ND;
        unsigned long long best = 0xFFFFFFFFFFFFFFFFULL;
#pragma unroll 1
        for (int jj = 0; jj < 8; ++jj) {
            const int col = jj * 64 + lane;
            const float* __restrict__ wr = wtf + (size_t)col * ND;
            float t = w2h[f * NK + col];
#pragma unroll
            for (int d = 0; d < ND; d += 4) {
                float4 xv = *(const float4*)(xr + d);   // broadcast
                float4 wv = *(const float4*)(wr + d);
                t = fmaf(-xv.x, wv.x, t);
                t = fmaf(-xv.y, wv.y, t);
                t = fmaf(-xv.z, wv.z, t);
                t = fmaf(-xv.w, wv.w, t);
            }
            unsigned int u = __float_as_uint(t);
            u ^= (unsigned int)((int)u >> 31) | 0x80000000u;
            const unsigned long long key =
                ((unsigned long long)u << 32) | (unsigned int)col;
            best = key < best ? key : best;
        }
#pragma unroll
        for (int off = 32; off > 0; off >>= 1) {
            const unsigned long long o = __shfl_xor(best, off, 64);
            best = o < best ? o : best;
        }
        if (lane == 0) keys[g] = (unsigned int)(best & 0xFFFFFFFFULL);
    }
}

// ---------------------------------------------------------------------------
// gather: 4 threads per row; straight-through output. Per-block loss partial
// (plain store, no atomics). 2048 blocks.
// ---------------------------------------------------------------------------
__global__ __launch_bounds__(256)
void vq_gather(const float* __restrict__ x_in, const float* __restrict__ wt,
               const unsigned int* __restrict__ keys, float* __restrict__ out,
               float* __restrict__ partial) {
    const int gid = blockIdx.x * 256 + threadIdx.x;   // [0, NF*NN*4)
    const int row = gid >> 2;
    const int c   = (gid & 3) * 16;
    const int f   = row >> 12;
    const unsigned int k = keys[row];

    const float* __restrict__ q16 = wt + ((size_t)f * NK + k) * ND + c;
    const float* __restrict__ x16 = x_in + (size_t)row * ND + c;
    float* __restrict__ o16       = out + (size_t)row * ND + c;

    float lsum = 0.0f;
#pragma unroll
    for (int jj = 0; jj < 4; ++jj) {
        float4 qv = *(const float4*)(q16 + 4 * jj);
        float4 xv = *(const float4*)(x16 + 4 * jj);
        const float dx0 = qv.x - xv.x;
        const float dx1 = qv.y - xv.y;
        const float dx2 = qv.z - xv.z;
        const float dx3 = qv.w - xv.w;
        lsum = fmaf(dx0, dx0, lsum);
        lsum = fmaf(dx1, dx1, lsum);
        lsum = fmaf(dx2, dx2, lsum);
        lsum = fmaf(dx3, dx3, lsum);
        *(float4*)(o16 + 4 * jj) = qv;
    }

#pragma unroll
    for (int off = 32; off > 0; off >>= 1) {
        lsum += __shfl_down(lsum, off, 64);
    }
    __shared__ float wsum[4];
    if ((threadIdx.x & 63) == 0) wsum[threadIdx.x >> 6] = lsum;
    __syncthreads();
    if (threadIdx.x == 0) {
        partial[blockIdx.x] = wsum[0] + wsum[1] + wsum[2] + wsum[3];
    }
}

// ---------------------------------------------------------------------------
// loss_final: sum 2048 partials -> loss scalar. 1 block.
// ---------------------------------------------------------------------------
__global__ __launch_bounds__(256)
void vq_loss_final(const float* __restrict__ partial, float* __restrict__ loss) {
    float s = 0.0f;
    for (int i = threadIdx.x; i < NPARTIAL; i += 256) s += partial[i];
#pragma unroll
    for (int off = 32; off > 0; off >>= 1) s += __shfl_down(s, off, 64);
    __shared__ float wsum[4];
    if ((threadIdx.x & 63) == 0) wsum[threadIdx.x >> 6] = s;
    __syncthreads();
    if (threadIdx.x == 0) {
        *loss = (wsum[0] + wsum[1] + wsum[2] + wsum[3]) * LOSS_SCALE;
    }
}

extern "C" void kernel_launch(void* const* d_in, const int* in_sizes, int n_in,
                              void* d_out, int out_size, void* d_ws, size_t ws_size,
                              hipStream_t stream) {
    const float* x_in = (const float*)d_in[0];  // [F, N, D] fp32
    const float* w    = (const float*)d_in[1];  // [F, D, K] fp32
    float* out        = (float*)d_out;          // [F*N*D] output then [1] loss

    float* wt  = (float*)d_ws;                                   // 4 MB
    float* w2h = wt + (size_t)NF * NK * ND;                      // 64 KB
    unsigned short* wh = (unsigned short*)(w2h + NF * NK);       // 2 MB
    unsigned short* wl = wh + (size_t)NF * NK * ND;              // 2 MB
    unsigned int* keys = (unsigned int*)(wl + (size_t)NF * NK * ND); // 512 KB
    unsigned char* flags = (unsigned char*)(keys + (size_t)NF * NN); // 128 KB
    float* partial = (float*)(flags + (size_t)NF * NN);          // 8 KB

    float* loss_slot = out + (size_t)NF * NN * ND;

    vq_prep_w<<<NF * NK * 8 / 256, 256, 0, stream>>>(w, wt, wh, wl, w2h);

    vq_argmin<<<NF * NN / 128, 512, 0, stream>>>(x_in, wh, wl, w2h, keys, flags);

    vq_rescue<<<NF * NN / 16 / 4, 256, 0, stream>>>(x_in, wt, w2h, flags, keys);

    vq_gather<<<NF * NN * 4 / 256, 256, 0, stream>>>(x_in, wt, keys, out, partial);

    vq_loss_final<<<1, 256, 0, stream>>>(partial, loss_slot);
}

// Round 2
// 165.809 us; speedup vs baseline: 2.4256x; 2.4256x over previous
//
#include <hip/hip_runtime.h>
#include <math.h>

#define NF 32
#define NN 4096
#define ND 64
#define NK 512

// loss = q_latent + 0.25 * e_latent = 1.25 * mean((q - x)^2)
#define LOSS_SCALE (1.25f / (float)(NF * NN * ND))
// rescue margin: rows with approx top-2 gap < TAU get exact fp32 re-argmin.
// 3-term split-bf16 score error: fp32-accum noise ~3e-5 + dropped lo*lo term
// <~1e-5; col-pack trunc e_t ~ 6e-5. Bound 4*e_a + 2*e_t ~ 2.6e-4 -> TAU 3e-4.
#define TAU 3e-4f

#define NPARTIAL (NF * NN * 4 / 256)   // 2048 gather blocks

typedef short bf16x8 __attribute__((ext_vector_type(8)));
typedef float f32x4 __attribute__((ext_vector_type(4)));

static __device__ __forceinline__ unsigned short f2bf_rne(float f) {
    unsigned int u = __float_as_uint(f);
    u += 0x7FFFu + ((u >> 16) & 1u);
    return (unsigned short)(u >> 16);
}
static __device__ __forceinline__ float bf2f(unsigned short h) {
    return __uint_as_float(((unsigned int)h) << 16);
}

// async global->LDS: 16B per lane, dest = wave-uniform base + lane*16
static __device__ __forceinline__ void gload_lds16(const void* g, void* l) {
    __builtin_amdgcn_global_load_lds(
        (const __attribute__((address_space(1))) unsigned int*)g,
        (__attribute__((address_space(3))) unsigned int*)l, 16, 0, 0);
}

// ---------------------------------------------------------------------------
// prep_w (fused): wt[f][k][d] = w[f][d][k]; wh/wl bf16 split; w2h = 0.5||w||^2
// via 8-lane shuffle reduce. thread per (f,k,dc): 512 blocks.
// ---------------------------------------------------------------------------
__global__ __launch_bounds__(256)
void vq_prep_w(const float* __restrict__ w, float* __restrict__ wt,
               unsigned short* __restrict__ wh, unsigned short* __restrict__ wl,
               float* __restrict__ w2h) {
    const int gid = blockIdx.x * 256 + threadIdx.x;   // [0, NF*NK*8)
    const int dc = gid & 7;
    const int k  = (gid >> 3) & (NK - 1);
    const int f  = gid >> 12;
    const float* __restrict__ wf = w + (size_t)f * ND * NK;
    const size_t rowo = ((size_t)f * NK + k) * ND + dc * 8;

    float v[8];
    unsigned short hh[8], ll[8];
    float s = 0.0f;
#pragma unroll
    for (int j = 0; j < 8; ++j) {
        v[j] = wf[(dc * 8 + j) * NK + k];
        s = fmaf(v[j], v[j], s);
        hh[j] = f2bf_rne(v[j]);
        ll[j] = f2bf_rne(v[j] - bf2f(hh[j]));
    }
    *(float4*)(wt + rowo)     = make_float4(v[0], v[1], v[2], v[3]);
    *(float4*)(wt + rowo + 4) = make_float4(v[4], v[5], v[6], v[7]);
    *(ushort4*)(wh + rowo)     = make_ushort4(hh[0], hh[1], hh[2], hh[3]);
    *(ushort4*)(wh + rowo + 4) = make_ushort4(hh[4], hh[5], hh[6], hh[7]);
    *(ushort4*)(wl + rowo)     = make_ushort4(ll[0], ll[1], ll[2], ll[3]);
    *(ushort4*)(wl + rowo + 4) = make_ushort4(ll[4], ll[5], ll[6], ll[7]);

    s += __shfl_xor(s, 1, 64);
    s += __shfl_xor(s, 2, 64);
    s += __shfl_xor(s, 4, 64);
    if (dc == 0) w2h[f * NK + k] = 0.5f * s;
}

// ---------------------------------------------------------------------------
// argmin v3: COLUMN-SPLIT ACROSS BLOCKS for occupancy, keeping the proven
// 256-thread / 60-VGPR wave structure (R1 lesson: __launch_bounds__(512,8)'s
// 64-VGPR cap spilled the loop-carried state -> 1.2 GB scratch traffic).
// Block = 4 waves x 32 rows = 128 rows, 256 cols (half of K). Grid 2048
// blocks = 8 blocks/CU = 32 waves/CU (VGPR 60 <= 64 -> 8 waves/SIMD; LDS
// ~17 KB x 8 = 136 KB <= 160 KB). Per-half exact top-2 (m1/m2) + packed-key
// kmin written to workspace; the rescue kernel merges the halves.
// 3-term split MFMA (xh*wh + xh*wl + xl*wh); acc init +0.5||w_k||^2.
// ---------------------------------------------------------------------------
__global__ __launch_bounds__(256, 4)
void vq_argmin(const float* __restrict__ x_in,
               const unsigned short* __restrict__ wh,
               const unsigned short* __restrict__ wl,
               const float* __restrict__ w2h,
               float* __restrict__ pm1,
               float* __restrict__ pm2,
               float* __restrict__ pkm) {
    const int b2   = blockIdx.x;          // [0, 2048)
    const int h    = b2 & 1;              // column half: adjacent blocks share x
    const int b    = b2 >> 1;             // [0, 1024)
    const int j    = b >> 3;              // [0, 128)
    const int f    = (b & 7) * 4 + (j & 3);
    const int xt   = j >> 2;              // [0, 32)
    const int tid  = threadIdx.x;
    const int wave = tid >> 6;
    const int lane = tid & 63;
    const int lc   = lane & 15;
    const int q    = lane >> 4;
    const int n0   = xt * 128 + wave * 32;   // wave's private 32 rows

    __shared__ float w2s[256];                                // 1 KB
    __shared__ __align__(16) unsigned short bstage[2][4096];  // 2 x 8 KB

    w2s[tid] = w2h[f * NK + h * 256 + tid];

    // ---- A-frags: 32 rows' (-x), split to bf16 hi/lo in-register.
    bf16x8 ah[2][2], al[2][2];
    const float* __restrict__ xbase = x_in + ((size_t)f * NN + n0 + lc) * ND;
#pragma unroll
    for (int mt = 0; mt < 2; ++mt) {
#pragma unroll
        for (int s = 0; s < 2; ++s) {
            const float* p = xbase + mt * 16 * ND + s * 32 + q * 8;
            float4 u0 = *(const float4*)(p);
            float4 u1 = *(const float4*)(p + 4);
            float xv[8] = {-u0.x, -u0.y, -u0.z, -u0.w, -u1.x, -u1.y, -u1.z, -u1.w};
            bf16x8 hh, ll;
#pragma unroll
            for (int jj = 0; jj < 8; ++jj) {
                unsigned short hb = f2bf_rne(xv[jj]);
                unsigned short lb = f2bf_rne(xv[jj] - bf2f(hb));
                hh[jj] = (short)hb;
                ll[jj] = (short)lb;
            }
            ah[mt][s] = hh;
            al[mt][s] = ll;
        }
    }

    const unsigned short* __restrict__ whf = wh + (size_t)f * NK * ND;
    const unsigned short* __restrict__ wlf = wl + (size_t)f * NK * ND;

    float m1[8], m2[8], kmin[8];
#pragma unroll
    for (int ri = 0; ri < 8; ++ri) { m1[ri] = INFINITY; m2[ri] = INFINITY; kmin[ri] = INFINITY; }

    // ---- stage supertile st (32 cols of this half) into bstage[pb]:
    // 8 chunks of 1KB, 2 per wave. chunk c = tl*4 + sg*2 + (lo/hi).
    // lane-linear dest (global_load_lds requirement).
#define STAGE(st, pb) do {                                                  \
    _Pragma("unroll")                                                       \
    for (int rep = 0; rep < 2; ++rep) {                                     \
        const int c  = wave * 2 + rep;                                      \
        const int tl = c >> 2;                                              \
        const int sg = (c >> 1) & 1;                                        \
        const unsigned short* src = ((c & 1) ? wlf : whf) +                 \
            (size_t)((h * 8 + (st)) * 32 + tl * 16 + lc) * ND + q * 8 + sg * 32; \
        gload_lds16(src, &bstage[pb][c * 512]);                             \
    }                                                                       \
} while (0)

    STAGE(0, 0);

    for (int st = 0; st < 8; ++st) {
        __syncthreads();                 // drains this st's loads (vmcnt)
        if (st < 7) STAGE(st + 1, (st + 1) & 1);
        const unsigned short* __restrict__ bb = &bstage[st & 1][0];

#pragma unroll
        for (int tl = 0; tl < 2; ++tl) {
            const int col = h * 256 + st * 32 + tl * 16 + lc;
            bf16x8 bh0 = *(const bf16x8*)(bb + (tl * 4 + 0) * 512 + lane * 8);
            bf16x8 bl0 = *(const bf16x8*)(bb + (tl * 4 + 1) * 512 + lane * 8);
            bf16x8 bh1 = *(const bf16x8*)(bb + (tl * 4 + 2) * 512 + lane * 8);
            bf16x8 bl1 = *(const bf16x8*)(bb + (tl * 4 + 3) * 512 + lane * 8);
            const float w2 = w2s[st * 32 + tl * 16 + lc];
#pragma unroll
            for (int mt = 0; mt < 2; ++mt) {
                f32x4 c = {w2, w2, w2, w2};
                c = __builtin_amdgcn_mfma_f32_16x16x32_bf16(ah[mt][0], bh0, c, 0, 0, 0);
                c = __builtin_amdgcn_mfma_f32_16x16x32_bf16(ah[mt][1], bh1, c, 0, 0, 0);
                c = __builtin_amdgcn_mfma_f32_16x16x32_bf16(ah[mt][0], bl0, c, 0, 0, 0);
                c = __builtin_amdgcn_mfma_f32_16x16x32_bf16(ah[mt][1], bl1, c, 0, 0, 0);
                c = __builtin_amdgcn_mfma_f32_16x16x32_bf16(al[mt][0], bh0, c, 0, 0, 0);
                c = __builtin_amdgcn_mfma_f32_16x16x32_bf16(al[mt][1], bh1, c, 0, 0, 0);
#pragma unroll
                for (int r = 0; r < 4; ++r) {
                    const int ri = mt * 4 + r;
                    const float sc = c[r];
                    // idx channel: col packed into low 9 mantissa bits
                    const float key = __uint_as_float(
                        (__float_as_uint(sc) & 0xFFFFFE00u) | (unsigned int)col);
                    kmin[ri] = fminf(kmin[ri], key);
                    // flag channel: exact top-2
                    m2[ri] = __builtin_amdgcn_fmed3f(sc, m1[ri], m2[ri]);
                    m1[ri] = fminf(sc, m1[ri]);
                }
            }
        }
    }

    // ---- merge top-2 + kmin across the 16 lanes holding each row ----
#pragma unroll
    for (int ri = 0; ri < 8; ++ri) {
        float a1 = m1[ri], a2 = m2[ri], ak = kmin[ri];
#pragma unroll
        for (int off = 1; off < 16; off <<= 1) {
            const float b1 = __shfl_xor(a1, off, 64);
            const float b2 = __shfl_xor(a2, off, 64);
            const float bk = __shfl_xor(ak, off, 64);
            a2 = fminf(fminf(a2, b2), fmaxf(a1, b1));
            a1 = fminf(a1, b1);
            ak = fminf(ak, bk);
        }
        m1[ri] = a1; m2[ri] = a2; kmin[ri] = ak;
    }

    // ---- write this half's partials (merge happens in vq_rescue) ----
    if (lc == 0) {
        const size_t FN = (size_t)NF * NN;
#pragma unroll
        for (int mt = 0; mt < 2; ++mt) {
            const int g = f * NN + n0 + mt * 16 + q * 4;   // 4 consecutive rows
            float4 v1 = make_float4(m1[mt*4+0], m1[mt*4+1], m1[mt*4+2], m1[mt*4+3]);
            float4 v2 = make_float4(m2[mt*4+0], m2[mt*4+1], m2[mt*4+2], m2[mt*4+3]);
            float4 vk = make_float4(kmin[mt*4+0], kmin[mt*4+1], kmin[mt*4+2], kmin[mt*4+3]);
            *(float4*)(pm1 + h * FN + g) = v1;
            *(float4*)(pm2 + h * FN + g) = v2;
            *(float4*)(pkm + h * FN + g) = vk;
        }
    }
}

// ---------------------------------------------------------------------------
// rescue v2: (a) merge the two column-halves' partials -> keys + flag,
// (b) exact fp32 full-K argmin for flagged rows. One wave per 16-row group
// (8192 waves). Ballot the flags, full-wave rescan per set row. No atomics.
// grid: 2048 blocks.
// ---------------------------------------------------------------------------
__global__ __launch_bounds__(256)
void vq_rescue(const float* __restrict__ x_in, const float* __restrict__ wt,
               const float* __restrict__ w2h,
               const float* __restrict__ pm1, const float* __restrict__ pm2,
               const float* __restrict__ pkm,
               unsigned int* __restrict__ keys) {
    const int lane = threadIdx.x & 63;
    const int wid  = (blockIdx.x * 256 + threadIdx.x) >> 6;  // [0, 8192)
    const int base = wid * 16;
    const size_t FN = (size_t)NF * NN;

    int flag = 0;
    if (lane < 16) {
        const int g = base + lane;
        const float a1 = pm1[g], b1 = pm1[FN + g];
        const float a2 = pm2[g], b2 = pm2[FN + g];
        const float ka = pkm[g], kb = pkm[FN + g];
        const float m1f = fminf(a1, b1);
        const float m2f = fminf(fminf(a2, b2), fmaxf(a1, b1));
        const float kf  = fminf(ka, kb);
        keys[g] = __float_as_uint(kf) & 0x1FFu;
        flag = (m2f - m1f < TAU) ? 1 : 0;
    }
    unsigned long long m = __ballot(flag != 0);
    while (m) {
        const int r = __ffsll(m) - 1;
        m &= m - 1;
        const int g = base + r;
        const int f = g >> 12;                               // / NN
        const float* __restrict__ xr  = x_in + (size_t)g * ND;
        const float* __restrict__ wtf = wt + (size_t)f * NK * ND;
        unsigned long long best = 0xFFFFFFFFFFFFFFFFULL;
#pragma unroll 1
        for (int jj = 0; jj < 8; ++jj) {
            const int col = jj * 64 + lane;
            const float* __restrict__ wr = wtf + (size_t)col * ND;
            float t = w2h[f * NK + col];
#pragma unroll
            for (int d = 0; d < ND; d += 4) {
                float4 xv = *(const float4*)(xr + d);   // broadcast
                float4 wv = *(const float4*)(wr + d);
                t = fmaf(-xv.x, wv.x, t);
                t = fmaf(-xv.y, wv.y, t);
                t = fmaf(-xv.z, wv.z, t);
                t = fmaf(-xv.w, wv.w, t);
            }
            unsigned int u = __float_as_uint(t);
            u ^= (unsigned int)((int)u >> 31) | 0x80000000u;
            const unsigned long long key =
                ((unsigned long long)u << 32) | (unsigned int)col;
            best = key < best ? key : best;
        }
#pragma unroll
        for (int off = 32; off > 0; off >>= 1) {
            const unsigned long long o = __shfl_xor(best, off, 64);
            best = o < best ? o : best;
        }
        if (lane == 0) keys[g] = (unsigned int)(best & 0xFFFFFFFFULL);
    }
}

// ---------------------------------------------------------------------------
// gather: 4 threads per row; straight-through output. Per-block loss partial
// (plain store, no atomics). 2048 blocks.
// ---------------------------------------------------------------------------
__global__ __launch_bounds__(256)
void vq_gather(const float* __restrict__ x_in, const float* __restrict__ wt,
               const unsigned int* __restrict__ keys, float* __restrict__ out,
               float* __restrict__ partial) {
    const int gid = blockIdx.x * 256 + threadIdx.x;   // [0, NF*NN*4)
    const int row = gid >> 2;
    const int c   = (gid & 3) * 16;
    const int f   = row >> 12;
    const unsigned int k = keys[row];

    const float* __restrict__ q16 = wt + ((size_t)f * NK + k) * ND + c;
    const float* __restrict__ x16 = x_in + (size_t)row * ND + c;
    float* __restrict__ o16       = out + (size_t)row * ND + c;

    float lsum = 0.0f;
#pragma unroll
    for (int jj = 0; jj < 4; ++jj) {
        float4 qv = *(const float4*)(q16 + 4 * jj);
        float4 xv = *(const float4*)(x16 + 4 * jj);
        const float dx0 = qv.x - xv.x;
        const float dx1 = qv.y - xv.y;
        const float dx2 = qv.z - xv.z;
        const float dx3 = qv.w - xv.w;
        lsum = fmaf(dx0, dx0, lsum);
        lsum = fmaf(dx1, dx1, lsum);
        lsum = fmaf(dx2, dx2, lsum);
        lsum = fmaf(dx3, dx3, lsum);
        *(float4*)(o16 + 4 * jj) = qv;
    }

#pragma unroll
    for (int off = 32; off > 0; off >>= 1) {
        lsum += __shfl_down(lsum, off, 64);
    }
    __shared__ float wsum[4];
    if ((threadIdx.x & 63) == 0) wsum[threadIdx.x >> 6] = lsum;
    __syncthreads();
    if (threadIdx.x == 0) {
        partial[blockIdx.x] = wsum[0] + wsum[1] + wsum[2] + wsum[3];
    }
}

// ---------------------------------------------------------------------------
// loss_final: sum 2048 partials -> loss scalar. 1 block.
// ---------------------------------------------------------------------------
__global__ __launch_bounds__(256)
void vq_loss_final(const float* __restrict__ partial, float* __restrict__ loss) {
    float s = 0.0f;
    for (int i = threadIdx.x; i < NPARTIAL; i += 256) s += partial[i];
#pragma unroll
    for (int off = 32; off > 0; off >>= 1) s += __shfl_down(s, off, 64);
    __shared__ float wsum[4];
    if ((threadIdx.x & 63) == 0) wsum[threadIdx.x >> 6] = s;
    __syncthreads();
    if (threadIdx.x == 0) {
        *loss = (wsum[0] + wsum[1] + wsum[2] + wsum[3]) * LOSS_SCALE;
    }
}

extern "C" void kernel_launch(void* const* d_in, const int* in_sizes, int n_in,
                              void* d_out, int out_size, void* d_ws, size_t ws_size,
                              hipStream_t stream) {
    const float* x_in = (const float*)d_in[0];  // [F, N, D] fp32
    const float* w    = (const float*)d_in[1];  // [F, D, K] fp32
    float* out        = (float*)d_out;          // [F*N*D] output then [1] loss

    float* wt  = (float*)d_ws;                                   // 4 MB
    float* w2h = wt + (size_t)NF * NK * ND;                      // 64 KB
    unsigned short* wh = (unsigned short*)(w2h + NF * NK);       // 2 MB
    unsigned short* wl = wh + (size_t)NF * NK * ND;              // 2 MB
    unsigned int* keys = (unsigned int*)(wl + (size_t)NF * NK * ND); // 512 KB
    float* pm1 = (float*)(keys + (size_t)NF * NN);               // 1 MB (2 halves)
    float* pm2 = pm1 + (size_t)2 * NF * NN;                      // 1 MB
    float* pkm = pm2 + (size_t)2 * NF * NN;                      // 1 MB
    float* partial = pkm + (size_t)2 * NF * NN;                  // 8 KB

    float* loss_slot = out + (size_t)NF * NN * ND;

    vq_prep_w<<<NF * NK * 8 / 256, 256, 0, stream>>>(w, wt, wh, wl, w2h);

    vq_argmin<<<NF * NN / 64, 256, 0, stream>>>(x_in, wh, wl, w2h, pm1, pm2, pkm);

    vq_rescue<<<NF * NN / 16 / 4, 256, 0, stream>>>(x_in, wt, w2h, pm1, pm2, pkm, keys);

    vq_gather<<<NF * NN * 4 / 256, 256, 0, stream>>>(x_in, wt, keys, out, partial);

    vq_loss_final<<<1, 256, 0, stream>>>(partial, loss_slot);
}

// Round 3
// 163.249 us; speedup vs baseline: 2.4636x; 1.0157x over previous
//
#include <hip/hip_runtime.h>
#include <math.h>

#define NF 32
#define NN 4096
#define ND 64
#define NK 512

// loss = q_latent + 0.25 * e_latent = 1.25 * mean((q - x)^2)
#define LOSS_SCALE (1.25f / (float)(NF * NN * ND))
// rescue margin: rows with approx top-2 gap < TAU get exact fp32 re-argmin.
// 3-term split-bf16 score error: fp32-accum noise ~3e-5 + dropped lo*lo term
// <~1e-5; col-pack trunc e_t ~ 6e-5. Bound 4*e_a + 2*e_t ~ 2.6e-4 -> TAU 3e-4.
#define TAU 3e-4f

#define NPARTIAL (NF * NN * 4 / 256)   // 2048 gather blocks

typedef short bf16x8 __attribute__((ext_vector_type(8)));
typedef float f32x4 __attribute__((ext_vector_type(4)));

static __device__ __forceinline__ unsigned short f2bf_rne(float f) {
    unsigned int u = __float_as_uint(f);
    u += 0x7FFFu + ((u >> 16) & 1u);
    return (unsigned short)(u >> 16);
}
static __device__ __forceinline__ float bf2f(unsigned short h) {
    return __uint_as_float(((unsigned int)h) << 16);
}

// ---------------------------------------------------------------------------
// prep_w (fused): wt[f][k][d] = w[f][d][k] fp32 (for rescue/gather);
// wpk = bf16 hi/lo split in MFMA-fragment-packed layout:
//   per f, col-tile ct (16 cols), chunk c in {0:hi s0, 1:hi s1, 2:lo s0,
//   3:lo s1}, lane = q*16+lc, 8 ushorts. A wave's 4 fragment loads for one
//   col-tile are 4 consecutive lane-linear 1KB blocks -> perfectly coalesced
//   global_load_dwordx4 with immediate offsets, no LDS staging needed.
// w2h = 0.5||w||^2 via 8-lane shuffle reduce. thread per (f,k,dc): 512 blocks.
// ---------------------------------------------------------------------------
__global__ __launch_bounds__(256)
void vq_prep_w(const float* __restrict__ w, float* __restrict__ wt,
               unsigned short* __restrict__ wpk, float* __restrict__ w2h) {
    const int gid = blockIdx.x * 256 + threadIdx.x;   // [0, NF*NK*8)
    const int dc = gid & 7;
    const int k  = (gid >> 3) & (NK - 1);
    const int f  = gid >> 12;
    const float* __restrict__ wf = w + (size_t)f * ND * NK;
    const size_t rowo = ((size_t)f * NK + k) * ND + dc * 8;

    float v[8];
    unsigned short hh[8], ll[8];
    float s = 0.0f;
#pragma unroll
    for (int j = 0; j < 8; ++j) {
        v[j] = wf[(dc * 8 + j) * NK + k];
        s = fmaf(v[j], v[j], s);
        hh[j] = f2bf_rne(v[j]);
        ll[j] = f2bf_rne(v[j] - bf2f(hh[j]));
    }
    *(float4*)(wt + rowo)     = make_float4(v[0], v[1], v[2], v[3]);
    *(float4*)(wt + rowo + 4) = make_float4(v[4], v[5], v[6], v[7]);

    // packed-fragment destinations
    const int lc  = k & 15;
    const int ct  = k >> 4;          // [0, 32)
    const int sdx = dc >> 2;         // d-subrange: 0 -> d<32, 1 -> d>=32
    const int qq  = dc & 3;          // q within subrange
    const int ln  = qq * 16 + lc;    // MFMA lane
    unsigned short* dsth = wpk + ((((size_t)f * 32 + ct) * 4 + sdx) * 64 + ln) * 8;
    unsigned short* dstl = wpk + ((((size_t)f * 32 + ct) * 4 + 2 + sdx) * 64 + ln) * 8;
    *(ushort4*)(dsth)     = make_ushort4(hh[0], hh[1], hh[2], hh[3]);
    *(ushort4*)(dsth + 4) = make_ushort4(hh[4], hh[5], hh[6], hh[7]);
    *(ushort4*)(dstl)     = make_ushort4(ll[0], ll[1], ll[2], ll[3]);
    *(ushort4*)(dstl + 4) = make_ushort4(ll[4], ll[5], ll[6], ll[7]);

    s += __shfl_xor(s, 1, 64);
    s += __shfl_xor(s, 2, 64);
    s += __shfl_xor(s, 4, 64);
    if (dc == 0) w2h[f * NK + k] = 0.5f * s;
}

// ---------------------------------------------------------------------------
// argmin v4: NO LDS STAGING, NO MAIN-LOOP BARRIERS. R2 post-mortem: the
// per-supertile __syncthreads + vmcnt(0) drain was the limiter (achieved
// residency ~2.4 blocks/CU regardless of grid; each barrier interval has
// ~500 cyc compute vs ~full load latency). The per-f codebook (128 KB
// hi+lo) is read by 64 blocks -> it lives in L2; staging it through LDS
// bought x4 intra-block reuse but cost barrier convoy serialization
// (guide: don't LDS-stage data that cache-fits).
// Block = 4 waves x 32 rows, 256 cols (half of K). Waves fully independent:
// B-fragments loaded straight from the packed wpk layout (4 x 1KB
// global_load_dwordx4 per col-tile, one base + imm offsets), 2-deep
// register pipeline over 16 col-tiles. One barrier total (w2 broadcast).
// 3-term split MFMA; acc init +0.5||w_k||^2; exact top-2 + packed kmin;
// halves merged in vq_rescue.
// ---------------------------------------------------------------------------
__global__ __launch_bounds__(256, 4)
void vq_argmin(const float* __restrict__ x_in,
               const unsigned short* __restrict__ wpk,
               const float* __restrict__ w2h,
               float* __restrict__ pm1,
               float* __restrict__ pm2,
               float* __restrict__ pkm) {
    const int b2   = blockIdx.x;          // [0, 2048)
    const int h    = b2 & 1;              // column half
    const int b    = b2 >> 1;             // [0, 1024)
    const int j    = b >> 3;              // [0, 128)
    const int f    = (b & 7) * 4 + (j & 3);
    const int xt   = j >> 2;              // [0, 32)
    const int tid  = threadIdx.x;
    const int wave = tid >> 6;
    const int lane = tid & 63;
    const int lc   = lane & 15;
    const int q    = lane >> 4;
    const int n0   = xt * 128 + wave * 32;   // wave's private 32 rows

    __shared__ float w2s[256];            // 1 KB total LDS

    w2s[tid] = w2h[f * NK + h * 256 + tid];

    // ---- A-frags: 32 rows' (-x), split to bf16 hi/lo in-register.
    bf16x8 ah[2][2], al[2][2];
    const float* __restrict__ xbase = x_in + ((size_t)f * NN + n0 + lc) * ND;
#pragma unroll
    for (int mt = 0; mt < 2; ++mt) {
#pragma unroll
        for (int s = 0; s < 2; ++s) {
            const float* p = xbase + mt * 16 * ND + s * 32 + q * 8;
            float4 u0 = *(const float4*)(p);
            float4 u1 = *(const float4*)(p + 4);
            float xv[8] = {-u0.x, -u0.y, -u0.z, -u0.w, -u1.x, -u1.y, -u1.z, -u1.w};
            bf16x8 hh, ll;
#pragma unroll
            for (int jj = 0; jj < 8; ++jj) {
                unsigned short hb = f2bf_rne(xv[jj]);
                unsigned short lb = f2bf_rne(xv[jj] - bf2f(hb));
                hh[jj] = (short)hb;
                ll[jj] = (short)lb;
            }
            ah[mt][s] = hh;
            al[mt][s] = ll;
        }
    }

    __syncthreads();                      // w2s ready; only barrier

    float m1[8], m2[8], kmin[8];
#pragma unroll
    for (int ri = 0; ri < 8; ++ri) { m1[ri] = INFINITY; m2[ri] = INFINITY; kmin[ri] = INFINITY; }

    // per-lane fragment base for this (f, h): col-tile stride = 4*512 ushorts
    const unsigned short* __restrict__ wf =
        wpk + (size_t)f * (32 * 4 * 512) + (size_t)h * 16 * 2048 + lane * 8;

    // ---- 2-deep register pipeline over 16 col-tiles (fully unrolled:
    // static indices only, no scratch) ----
    bf16x8 c0, c1, c2, c3;
    {
        const unsigned short* p = wf;
        c0 = *(const bf16x8*)(p);
        c1 = *(const bf16x8*)(p + 512);
        c2 = *(const bf16x8*)(p + 1024);
        c3 = *(const bf16x8*)(p + 1536);
    }
#pragma unroll
    for (int ct2 = 0; ct2 < 16; ++ct2) {
        bf16x8 n0, n1, n2, n3;
        if (ct2 < 15) {
            const unsigned short* p = wf + (size_t)(ct2 + 1) * 2048;
            n0 = *(const bf16x8*)(p);
            n1 = *(const bf16x8*)(p + 512);
            n2 = *(const bf16x8*)(p + 1024);
            n3 = *(const bf16x8*)(p + 1536);
        }
        const int col = h * 256 + ct2 * 16 + lc;
        const float w2 = w2s[ct2 * 16 + lc];
#pragma unroll
        for (int mt = 0; mt < 2; ++mt) {
            f32x4 c = {w2, w2, w2, w2};
            c = __builtin_amdgcn_mfma_f32_16x16x32_bf16(ah[mt][0], c0, c, 0, 0, 0);
            c = __builtin_amdgcn_mfma_f32_16x16x32_bf16(ah[mt][1], c1, c, 0, 0, 0);
            c = __builtin_amdgcn_mfma_f32_16x16x32_bf16(ah[mt][0], c2, c, 0, 0, 0);
            c = __builtin_amdgcn_mfma_f32_16x16x32_bf16(ah[mt][1], c3, c, 0, 0, 0);
            c = __builtin_amdgcn_mfma_f32_16x16x32_bf16(al[mt][0], c0, c, 0, 0, 0);
            c = __builtin_amdgcn_mfma_f32_16x16x32_bf16(al[mt][1], c1, c, 0, 0, 0);
#pragma unroll
            for (int r = 0; r < 4; ++r) {
                const int ri = mt * 4 + r;
                const float sc = c[r];
                // idx channel: col packed into low 9 mantissa bits
                const float key = __uint_as_float(
                    (__float_as_uint(sc) & 0xFFFFFE00u) | (unsigned int)col);
                kmin[ri] = fminf(kmin[ri], key);
                // flag channel: exact top-2
                m2[ri] = __builtin_amdgcn_fmed3f(sc, m1[ri], m2[ri]);
                m1[ri] = fminf(sc, m1[ri]);
            }
        }
        c0 = n0; c1 = n1; c2 = n2; c3 = n3;
    }

    // ---- merge top-2 + kmin across the 16 lanes holding each row ----
#pragma unroll
    for (int ri = 0; ri < 8; ++ri) {
        float a1 = m1[ri], a2 = m2[ri], ak = kmin[ri];
#pragma unroll
        for (int off = 1; off < 16; off <<= 1) {
            const float b1 = __shfl_xor(a1, off, 64);
            const float b2 = __shfl_xor(a2, off, 64);
            const float bk = __shfl_xor(ak, off, 64);
            a2 = fminf(fminf(a2, b2), fmaxf(a1, b1));
            a1 = fminf(a1, b1);
            ak = fminf(ak, bk);
        }
        m1[ri] = a1; m2[ri] = a2; kmin[ri] = ak;
    }

    // ---- write this half's partials (merge happens in vq_rescue) ----
    if (lc == 0) {
        const size_t FN = (size_t)NF * NN;
#pragma unroll
        for (int mt = 0; mt < 2; ++mt) {
            const int g = f * NN + n0 + mt * 16 + q * 4;   // 4 consecutive rows
            float4 v1 = make_float4(m1[mt*4+0], m1[mt*4+1], m1[mt*4+2], m1[mt*4+3]);
            float4 v2 = make_float4(m2[mt*4+0], m2[mt*4+1], m2[mt*4+2], m2[mt*4+3]);
            float4 vk = make_float4(kmin[mt*4+0], kmin[mt*4+1], kmin[mt*4+2], kmin[mt*4+3]);
            *(float4*)(pm1 + h * FN + g) = v1;
            *(float4*)(pm2 + h * FN + g) = v2;
            *(float4*)(pkm + h * FN + g) = vk;
        }
    }
}

// ---------------------------------------------------------------------------
// rescue v2: (a) merge the two column-halves' partials -> keys + flag,
// (b) exact fp32 full-K argmin for flagged rows. One wave per 16-row group
// (8192 waves). Ballot the flags, full-wave rescan per set row. No atomics.
// grid: 2048 blocks.
// ---------------------------------------------------------------------------
__global__ __launch_bounds__(256)
void vq_rescue(const float* __restrict__ x_in, const float* __restrict__ wt,
               const float* __restrict__ w2h,
               const float* __restrict__ pm1, const float* __restrict__ pm2,
               const float* __restrict__ pkm,
               unsigned int* __restrict__ keys) {
    const int lane = threadIdx.x & 63;
    const int wid  = (blockIdx.x * 256 + threadIdx.x) >> 6;  // [0, 8192)
    const int base = wid * 16;
    const size_t FN = (size_t)NF * NN;

    int flag = 0;
    if (lane < 16) {
        const int g = base + lane;
        const float a1 = pm1[g], b1 = pm1[FN + g];
        const float a2 = pm2[g], b2 = pm2[FN + g];
        const float ka = pkm[g], kb = pkm[FN + g];
        const float m1f = fminf(a1, b1);
        const float m2f = fminf(fminf(a2, b2), fmaxf(a1, b1));
        const float kf  = fminf(ka, kb);
        keys[g] = __float_as_uint(kf) & 0x1FFu;
        flag = (m2f - m1f < TAU) ? 1 : 0;
    }
    unsigned long long m = __ballot(flag != 0);
    while (m) {
        const int r = __ffsll(m) - 1;
        m &= m - 1;
        const int g = base + r;
        const int f = g >> 12;                               // / NN
        const float* __restrict__ xr  = x_in + (size_t)g * ND;
        const float* __restrict__ wtf = wt + (size_t)f * NK * ND;
        unsigned long long best = 0xFFFFFFFFFFFFFFFFULL;
#pragma unroll 1
        for (int jj = 0; jj < 8; ++jj) {
            const int col = jj * 64 + lane;
            const float* __restrict__ wr = wtf + (size_t)col * ND;
            float t = w2h[f * NK + col];
#pragma unroll
            for (int d = 0; d < ND; d += 4) {
                float4 xv = *(const float4*)(xr + d);   // broadcast
                float4 wv = *(const float4*)(wr + d);
                t = fmaf(-xv.x, wv.x, t);
                t = fmaf(-xv.y, wv.y, t);
                t = fmaf(-xv.z, wv.z, t);
                t = fmaf(-xv.w, wv.w, t);
            }
            unsigned int u = __float_as_uint(t);
            u ^= (unsigned int)((int)u >> 31) | 0x80000000u;
            const unsigned long long key =
                ((unsigned long long)u << 32) | (unsigned int)col;
            best = key < best ? key : best;
        }
#pragma unroll
        for (int off = 32; off > 0; off >>= 1) {
            const unsigned long long o = __shfl_xor(best, off, 64);
            best = o < best ? o : best;
        }
        if (lane == 0) keys[g] = (unsigned int)(best & 0xFFFFFFFFULL);
    }
}

// ---------------------------------------------------------------------------
// gather: 4 threads per row; straight-through output. Per-block loss partial
// (plain store, no atomics). 2048 blocks.
// ---------------------------------------------------------------------------
__global__ __launch_bounds__(256)
void vq_gather(const float* __restrict__ x_in, const float* __restrict__ wt,
               const unsigned int* __restrict__ keys, float* __restrict__ out,
               float* __restrict__ partial) {
    const int gid = blockIdx.x * 256 + threadIdx.x;   // [0, NF*NN*4)
    const int row = gid >> 2;
    const int c   = (gid & 3) * 16;
    const int f   = row >> 12;
    const unsigned int k = keys[row];

    const float* __restrict__ q16 = wt + ((size_t)f * NK + k) * ND + c;
    const float* __restrict__ x16 = x_in + (size_t)row * ND + c;
    float* __restrict__ o16       = out + (size_t)row * ND + c;

    float lsum = 0.0f;
#pragma unroll
    for (int jj = 0; jj < 4; ++jj) {
        float4 qv = *(const float4*)(q16 + 4 * jj);
        float4 xv = *(const float4*)(x16 + 4 * jj);
        const float dx0 = qv.x - xv.x;
        const float dx1 = qv.y - xv.y;
        const float dx2 = qv.z - xv.z;
        const float dx3 = qv.w - xv.w;
        lsum = fmaf(dx0, dx0, lsum);
        lsum = fmaf(dx1, dx1, lsum);
        lsum = fmaf(dx2, dx2, lsum);
        lsum = fmaf(dx3, dx3, lsum);
        *(float4*)(o16 + 4 * jj) = qv;
    }

#pragma unroll
    for (int off = 32; off > 0; off >>= 1) {
        lsum += __shfl_down(lsum, off, 64);
    }
    __shared__ float wsum[4];
    if ((threadIdx.x & 63) == 0) wsum[threadIdx.x >> 6] = lsum;
    __syncthreads();
    if (threadIdx.x == 0) {
        partial[blockIdx.x] = wsum[0] + wsum[1] + wsum[2] + wsum[3];
    }
}

// ---------------------------------------------------------------------------
// loss_final: sum 2048 partials -> loss scalar. 1 block.
// ---------------------------------------------------------------------------
__global__ __launch_bounds__(256)
void vq_loss_final(const float* __restrict__ partial, float* __restrict__ loss) {
    float s = 0.0f;
    for (int i = threadIdx.x; i < NPARTIAL; i += 256) s += partial[i];
#pragma unroll
    for (int off = 32; off > 0; off >>= 1) s += __shfl_down(s, off, 64);
    __shared__ float wsum[4];
    if ((threadIdx.x & 63) == 0) wsum[threadIdx.x >> 6] = s;
    __syncthreads();
    if (threadIdx.x == 0) {
        *loss = (wsum[0] + wsum[1] + wsum[2] + wsum[3]) * LOSS_SCALE;
    }
}

extern "C" void kernel_launch(void* const* d_in, const int* in_sizes, int n_in,
                              void* d_out, int out_size, void* d_ws, size_t ws_size,
                              hipStream_t stream) {
    const float* x_in = (const float*)d_in[0];  // [F, N, D] fp32
    const float* w    = (const float*)d_in[1];  // [F, D, K] fp32
    float* out        = (float*)d_out;          // [F*N*D] output then [1] loss

    float* wt  = (float*)d_ws;                                   // 4 MB
    float* w2h = wt + (size_t)NF * NK * ND;                      // 64 KB
    unsigned short* wpk = (unsigned short*)(w2h + NF * NK);      // 4 MB packed
    unsigned int* keys = (unsigned int*)(wpk + (size_t)2 * NF * NK * ND); // 512 KB
    float* pm1 = (float*)(keys + (size_t)NF * NN);               // 1 MB (2 halves)
    float* pm2 = pm1 + (size_t)2 * NF * NN;                      // 1 MB
    float* pkm = pm2 + (size_t)2 * NF * NN;                      // 1 MB
    float* partial = pkm + (size_t)2 * NF * NN;                  // 8 KB

    float* loss_slot = out + (size_t)NF * NN * ND;

    vq_prep_w<<<NF * NK * 8 / 256, 256, 0, stream>>>(w, wt, wpk, w2h);

    vq_argmin<<<NF * NN / 64, 256, 0, stream>>>(x_in, wpk, w2h, pm1, pm2, pkm);

    vq_rescue<<<NF * NN / 16 / 4, 256, 0, stream>>>(x_in, wt, w2h, pm1, pm2, pkm, keys);

    vq_gather<<<NF * NN * 4 / 256, 256, 0, stream>>>(x_in, wt, keys, out, partial);

    vq_loss_final<<<1, 256, 0, stream>>>(partial, loss_slot);
}